// Round 1
// baseline (1644.505 us; speedup 1.0000x reference)
//
#include <hip/hip_runtime.h>
#include <hip/hip_bf16.h>

#define D 128

// ---------------- setup kernels ----------------

__global__ void k_zero(int* __restrict__ p, int n) {
    int i = blockIdx.x * 256 + threadIdx.x;
    if (i < n) p[i] = 0;
}

__global__ void k_count(const int* __restrict__ dst, int* __restrict__ cnt, int e) {
    int i = blockIdx.x * 256 + threadIdx.x;
    if (i < e) atomicAdd(&cnt[dst[i]], 1);
}

__global__ void k_dinv(const int* __restrict__ cnt, float* __restrict__ dinv, int n) {
    int i = blockIdx.x * 256 + threadIdx.x;
    if (i < n) {
        float deg = (float)(cnt[i] + 2);   // +2 = improved self-loop weight
        dinv[i] = 1.0f / sqrtf(deg);
    }
}

// single-block exclusive scan of cnt[0..n) -> offsets[0..n], cursor copy
__global__ __launch_bounds__(1024) void k_scan(const int* __restrict__ cnt,
                                               int* __restrict__ offsets,
                                               int* __restrict__ cursor, int n) {
    __shared__ int sdata[1024];
    const int t = threadIdx.x;
    int running = 0;
    const int CH = 1024 * 8;
    for (int base = 0; base < n; base += CH) {
        int idx0 = base + t * 8;
        int v[8], pre[8];
        int sum = 0;
#pragma unroll
        for (int j = 0; j < 8; j++) {
            int ii = idx0 + j;
            v[j] = (ii < n) ? cnt[ii] : 0;
            pre[j] = sum;
            sum += v[j];
        }
        sdata[t] = sum;
        __syncthreads();
        // Hillis-Steele inclusive scan over 1024 thread sums
        for (int off = 1; off < 1024; off <<= 1) {
            int x = (t >= off) ? sdata[t - off] : 0;
            __syncthreads();
            sdata[t] += x;
            __syncthreads();
        }
        int thread_excl = sdata[t] - sum;
        int chunk_total = sdata[1023];
        __syncthreads();   // protect sdata before next chunk overwrites
#pragma unroll
        for (int j = 0; j < 8; j++) {
            int ii = idx0 + j;
            if (ii < n) {
                int o = running + thread_excl + pre[j];
                offsets[ii] = o;
                cursor[ii] = o;
            }
        }
        running += chunk_total;
    }
    if (t == 0) offsets[n] = running;
}

__global__ void k_fill(const int* __restrict__ src, const int* __restrict__ dst,
                       int* __restrict__ cursor, const float* __restrict__ dinv,
                       int* __restrict__ csr_src, float* __restrict__ csr_norm, int e) {
    int i = blockIdx.x * 256 + threadIdx.x;
    if (i < e) {
        int s = src[i];
        int d = dst[i];
        int pos = atomicAdd(&cursor[d], 1);
        csr_src[pos] = s;
        csr_norm[pos] = dinv[s] * dinv[d];
    }
}

// ---------------- matmul: O[r][c] = sum_k H[r][k] * W[k][c] ----------------
// 128 rows x 128 cols per 256-thread block; k in chunks of 32.
__global__ __launch_bounds__(256) void k_matmul(const float* __restrict__ H,
                                                const float* __restrict__ W,
                                                float* __restrict__ O, int nrows) {
    __shared__ float Ws[32 * D];    // Ws[k][c]
    __shared__ float HsT[32 * D];   // HsT[k][r]  (transposed for b128 row reads)
    const int t = threadIdx.x;
    const int row0 = blockIdx.x * 128;
    const int tx = t & 15;    // col group (8 cols)
    const int ty = t >> 4;    // row group (8 rows)

    float acc[8][8];
#pragma unroll
    for (int i = 0; i < 8; i++)
#pragma unroll
        for (int j = 0; j < 8; j++) acc[i][j] = 0.0f;

    const int r_st = t & 127;
    const int kb = (t >> 7) * 16;   // 0 or 16

    for (int kc = 0; kc < D; kc += 32) {
        // stage W chunk: 4096 floats = 1024 float4
        {
            const float4* W4 = (const float4*)(W + kc * D);
            float4* Ws4 = (float4*)Ws;
#pragma unroll
            for (int it = 0; it < 4; it++) Ws4[t + it * 256] = W4[t + it * 256];
        }
        // stage transposed H chunk
        {
            int gr = row0 + r_st;
            float4 v0, v1, v2, v3;
            if (gr < nrows) {
                const float4* Hp = (const float4*)(H + (size_t)gr * D + kc + kb);
                v0 = Hp[0]; v1 = Hp[1]; v2 = Hp[2]; v3 = Hp[3];
            } else {
                v0 = v1 = v2 = v3 = make_float4(0.f, 0.f, 0.f, 0.f);
            }
            float vals[16];
            *(float4*)&vals[0]  = v0;
            *(float4*)&vals[4]  = v1;
            *(float4*)&vals[8]  = v2;
            *(float4*)&vals[12] = v3;
#pragma unroll
            for (int j = 0; j < 16; j++) HsT[(kb + j) * 128 + r_st] = vals[j];
        }
        __syncthreads();
#pragma unroll
        for (int k = 0; k < 32; k++) {
            float4 a0 = *(const float4*)&HsT[k * 128 + ty * 8];
            float4 a1 = *(const float4*)&HsT[k * 128 + ty * 8 + 4];
            float4 b0 = *(const float4*)&Ws[k * D + tx * 8];
            float4 b1 = *(const float4*)&Ws[k * D + tx * 8 + 4];
            float ar[8] = {a0.x, a0.y, a0.z, a0.w, a1.x, a1.y, a1.z, a1.w};
            float br[8] = {b0.x, b0.y, b0.z, b0.w, b1.x, b1.y, b1.z, b1.w};
#pragma unroll
            for (int i = 0; i < 8; i++)
#pragma unroll
                for (int j = 0; j < 8; j++) acc[i][j] += ar[i] * br[j];
        }
        __syncthreads();
    }
#pragma unroll
    for (int i = 0; i < 8; i++) {
        int gr = row0 + ty * 8 + i;
        if (gr < nrows) {
            float4* Op = (float4*)(O + (size_t)gr * D + tx * 8);
            Op[0] = make_float4(acc[i][0], acc[i][1], acc[i][2], acc[i][3]);
            Op[1] = make_float4(acc[i][4], acc[i][5], acc[i][6], acc[i][7]);
        }
    }
}

// ---------------- gather: out[i] = b + 2*dinv[i]^2*T[i] + sum_e norm_e*T[src_e] ----
// one wave (64 lanes) per node; each lane owns cols lane and lane+64
__global__ __launch_bounds__(256) void k_gather(const float* __restrict__ T,
                                                const int* __restrict__ csr_src,
                                                const float* __restrict__ csr_norm,
                                                const int* __restrict__ offsets,
                                                const float* __restrict__ dinv,
                                                const float* __restrict__ bias,
                                                float* __restrict__ O, int n) {
    int node = blockIdx.x * 4 + (threadIdx.x >> 6);
    int lane = threadIdx.x & 63;
    if (node >= n) return;
    float di = dinv[node];
    float selfw = 2.0f * di * di;
    const float* Ti = T + (size_t)node * D;
    float a0 = selfw * Ti[lane];
    float a1 = selfw * Ti[lane + 64];
    int e0 = offsets[node];
    int e1 = offsets[node + 1];
    for (int e = e0; e < e1; e++) {
        int s = csr_src[e];
        float w = csr_norm[e];
        const float* Ts = T + (size_t)s * D;
        a0 += w * Ts[lane];
        a1 += w * Ts[lane + 64];
    }
    O[(size_t)node * D + lane]      = a0 + bias[lane];
    O[(size_t)node * D + lane + 64] = a1 + bias[lane + 64];
}

// ---------------- launch ----------------

extern "C" void kernel_launch(void* const* d_in, const int* in_sizes, int n_in,
                              void* d_out, int out_size, void* d_ws, size_t ws_size,
                              hipStream_t stream) {
    const float* x  = (const float*)d_in[0];
    const int*   ei = (const int*)d_in[1];
    const float* W1 = (const float*)d_in[2];
    const float* b1 = (const float*)d_in[3];
    const float* W2 = (const float*)d_in[4];
    const float* b2 = (const float*)d_in[5];
    const int N = in_sizes[0] / D;
    const int E = in_sizes[1] / 2;
    float* out = (float*)d_out;

    char* ws = (char*)d_ws;
    size_t woff = 0;
    auto alloc = [&](size_t bytes) -> void* {
        void* p = ws + woff;
        woff = (woff + bytes + 15) & ~(size_t)15;
        return p;
    };
    float* T        = (float*)alloc((size_t)N * D * sizeof(float));
    int*   cnt      = (int*)  alloc((size_t)N * sizeof(int));
    int*   offsets  = (int*)  alloc((size_t)(N + 1) * sizeof(int));
    int*   cursor   = (int*)  alloc((size_t)N * sizeof(int));
    float* dinv     = (float*)alloc((size_t)N * sizeof(float));
    int*   csr_src  = (int*)  alloc((size_t)E * sizeof(int));
    float* csr_norm = (float*)alloc((size_t)E * sizeof(float));
    (void)ws_size; (void)n_in; (void)out_size;

    const int* e_src = ei;
    const int* e_dst = ei + E;

    k_zero<<<(N + 255) / 256, 256, 0, stream>>>(cnt, N);
    k_count<<<(E + 255) / 256, 256, 0, stream>>>(e_dst, cnt, E);
    k_dinv<<<(N + 255) / 256, 256, 0, stream>>>(cnt, dinv, N);
    k_scan<<<1, 1024, 0, stream>>>(cnt, offsets, cursor, N);
    k_fill<<<(E + 255) / 256, 256, 0, stream>>>(e_src, e_dst, cursor, dinv,
                                                csr_src, csr_norm, E);

    const float* h = x;
    for (int l = 0; l < 5; l++) {
        const float* W = l ? W2 : W1;
        const float* b = l ? b2 : b1;
        k_matmul<<<(N + 127) / 128, 256, 0, stream>>>(h, W, T, N);
        k_gather<<<(N + 3) / 4, 256, 0, stream>>>(T, csr_src, csr_norm, offsets,
                                                  dinv, b, out, N);
        h = out;
    }
}

// Round 2
// 1139.551 us; speedup vs baseline: 1.4431x; 1.4431x over previous
//
#include <hip/hip_runtime.h>
#include <hip/hip_bf16.h>

#define D 128

// ---------------- setup kernels ----------------

__global__ void k_zero(int* __restrict__ p, int n) {
    int i = blockIdx.x * 256 + threadIdx.x;
    if (i < n) p[i] = 0;
}

__global__ void k_count(const int* __restrict__ dst, int* __restrict__ cnt, int e) {
    int i = blockIdx.x * 256 + threadIdx.x;
    if (i < e) atomicAdd(&cnt[dst[i]], 1);
}

__global__ void k_dinv(const int* __restrict__ cnt, float* __restrict__ dinv, int n) {
    int i = blockIdx.x * 256 + threadIdx.x;
    if (i < n) {
        float deg = (float)(cnt[i] + 2);   // +2 = improved self-loop weight
        dinv[i] = 1.0f / sqrtf(deg);
    }
}

// ---- hierarchical scan: A) per-block reduce, B) scan partials, C) rescan ----
// chunk = 512 elements per 256-thread block

__global__ __launch_bounds__(256) void k_scanA(const int* __restrict__ cnt,
                                               int* __restrict__ partials, int n) {
    __shared__ int s[256];
    int b = blockIdx.x, t = threadIdx.x;
    int i0 = b * 512 + t * 2;
    int v = 0;
    if (i0 < n) v += cnt[i0];
    if (i0 + 1 < n) v += cnt[i0 + 1];
    s[t] = v;
    __syncthreads();
    for (int off = 128; off > 0; off >>= 1) {
        if (t < off) s[t] += s[t + off];
        __syncthreads();
    }
    if (t == 0) partials[b] = s[0];
}

__global__ __launch_bounds__(512) void k_scanB(const int* __restrict__ partials,
                                               int* __restrict__ base,
                                               int* __restrict__ off_n, int nb) {
    __shared__ int s[512];
    int t = threadIdx.x;
    int v = (t < nb) ? partials[t] : 0;
    s[t] = v;
    __syncthreads();
    for (int off = 1; off < 512; off <<= 1) {
        int x = (t >= off) ? s[t - off] : 0;
        __syncthreads();
        s[t] += x;
        __syncthreads();
    }
    if (t < nb) base[t] = s[t] - v;          // exclusive
    if (t == nb - 1) off_n[0] = s[t];        // total = offsets[N]
}

__global__ __launch_bounds__(256) void k_scanC(const int* __restrict__ cnt,
                                               const int* __restrict__ base,
                                               int* __restrict__ offsets,
                                               int* __restrict__ cursor, int n) {
    __shared__ int s[256];
    int b = blockIdx.x, t = threadIdx.x;
    int i0 = b * 512 + t * 2;
    int v0 = (i0 < n) ? cnt[i0] : 0;
    int v1 = (i0 + 1 < n) ? cnt[i0 + 1] : 0;
    int sum = v0 + v1;
    s[t] = sum;
    __syncthreads();
    for (int off = 1; off < 256; off <<= 1) {
        int x = (t >= off) ? s[t - off] : 0;
        __syncthreads();
        s[t] += x;
        __syncthreads();
    }
    int excl = s[t] - sum + base[b];
    if (i0 < n) { offsets[i0] = excl; cursor[i0] = excl; }
    if (i0 + 1 < n) { offsets[i0 + 1] = excl + v0; cursor[i0 + 1] = excl + v0; }
}

__global__ void k_fill(const int* __restrict__ src, const int* __restrict__ dst,
                       int* __restrict__ cursor, const float* __restrict__ dinv,
                       int* __restrict__ csr_src, float* __restrict__ csr_norm, int e) {
    int i = blockIdx.x * 256 + threadIdx.x;
    if (i < e) {
        int s = src[i];
        int d = dst[i];
        int pos = atomicAdd(&cursor[d], 1);
        csr_src[pos] = s;
        csr_norm[pos] = dinv[s] * dinv[d];
    }
}

// ---------------- matmul: O[r][c] = sum_k H[r][k] * W[k][c] ----------------
__global__ __launch_bounds__(256) void k_matmul(const float* __restrict__ H,
                                                const float* __restrict__ W,
                                                float* __restrict__ O, int nrows) {
    __shared__ float Ws[32 * D];    // Ws[k][c]
    __shared__ float HsT[32 * D];   // HsT[k][r]
    const int t = threadIdx.x;
    const int row0 = blockIdx.x * 128;
    const int tx = t & 15;    // col group (8 cols)
    const int ty = t >> 4;    // row group (8 rows)

    float acc[8][8];
#pragma unroll
    for (int i = 0; i < 8; i++)
#pragma unroll
        for (int j = 0; j < 8; j++) acc[i][j] = 0.0f;

    const int r_st = t & 127;
    const int kb = (t >> 7) * 16;   // 0 or 16

    for (int kc = 0; kc < D; kc += 32) {
        {
            const float4* W4 = (const float4*)(W + kc * D);
            float4* Ws4 = (float4*)Ws;
#pragma unroll
            for (int it = 0; it < 4; it++) Ws4[t + it * 256] = W4[t + it * 256];
        }
        {
            int gr = row0 + r_st;
            float4 v0, v1, v2, v3;
            if (gr < nrows) {
                const float4* Hp = (const float4*)(H + (size_t)gr * D + kc + kb);
                v0 = Hp[0]; v1 = Hp[1]; v2 = Hp[2]; v3 = Hp[3];
            } else {
                v0 = v1 = v2 = v3 = make_float4(0.f, 0.f, 0.f, 0.f);
            }
            float vals[16];
            *(float4*)&vals[0]  = v0;
            *(float4*)&vals[4]  = v1;
            *(float4*)&vals[8]  = v2;
            *(float4*)&vals[12] = v3;
#pragma unroll
            for (int j = 0; j < 16; j++) HsT[(kb + j) * 128 + r_st] = vals[j];
        }
        __syncthreads();
#pragma unroll 8
        for (int k = 0; k < 32; k++) {
            float4 a0 = *(const float4*)&HsT[k * 128 + ty * 8];
            float4 a1 = *(const float4*)&HsT[k * 128 + ty * 8 + 4];
            float4 b0 = *(const float4*)&Ws[k * D + tx * 8];
            float4 b1 = *(const float4*)&Ws[k * D + tx * 8 + 4];
            float ar[8] = {a0.x, a0.y, a0.z, a0.w, a1.x, a1.y, a1.z, a1.w};
            float br[8] = {b0.x, b0.y, b0.z, b0.w, b1.x, b1.y, b1.z, b1.w};
#pragma unroll
            for (int i = 0; i < 8; i++)
#pragma unroll
                for (int j = 0; j < 8; j++) acc[i][j] += ar[i] * br[j];
        }
        __syncthreads();
    }
#pragma unroll
    for (int i = 0; i < 8; i++) {
        int gr = row0 + ty * 8 + i;
        if (gr < nrows) {
            float4* Op = (float4*)(O + (size_t)gr * D + tx * 8);
            Op[0] = make_float4(acc[i][0], acc[i][1], acc[i][2], acc[i][3]);
            Op[1] = make_float4(acc[i][4], acc[i][5], acc[i][6], acc[i][7]);
        }
    }
}

// ---------------- gather ----------------
// one wave per node; half-wave per edge (32 lanes x float4 = 512B row);
// 2 edges/iter, unrolled x2 -> 4 independent 1KiB dual-row loads in flight.
__global__ __launch_bounds__(256) void k_gather(const float* __restrict__ T,
                                                const int* __restrict__ csr_src,
                                                const float* __restrict__ csr_norm,
                                                const int* __restrict__ offsets,
                                                const float* __restrict__ dinv,
                                                const float* __restrict__ bias,
                                                float* __restrict__ O, int n) {
    int node = blockIdx.x * 4 + (threadIdx.x >> 6);
    if (node >= n) return;
    int lane = threadIdx.x & 63;
    int half = lane >> 5;            // 0 or 1
    int c = (lane & 31) << 2;        // col base (float4)
    const float* Tc = T + c;

    float ax = 0.f, ay = 0.f, az = 0.f, aw = 0.f;
    if (half == 0) {
        float di = dinv[node];
        float sw = 2.0f * di * di;
        float4 v = *(const float4*)(Tc + (size_t)node * D);
        ax = sw * v.x; ay = sw * v.y; az = sw * v.z; aw = sw * v.w;
    }

    int e = offsets[node];
    const int e1 = offsets[node + 1];

    // 8 edges per group: 4 independent dual-row loads
    for (; e + 8 <= e1; e += 8) {
        int i0 = e + half, i1 = e + 2 + half, i2 = e + 4 + half, i3 = e + 6 + half;
        int s0 = csr_src[i0]; float w0 = csr_norm[i0];
        int s1 = csr_src[i1]; float w1 = csr_norm[i1];
        int s2 = csr_src[i2]; float w2 = csr_norm[i2];
        int s3 = csr_src[i3]; float w3 = csr_norm[i3];
        float4 v0 = *(const float4*)(Tc + (size_t)s0 * D);
        float4 v1 = *(const float4*)(Tc + (size_t)s1 * D);
        float4 v2 = *(const float4*)(Tc + (size_t)s2 * D);
        float4 v3 = *(const float4*)(Tc + (size_t)s3 * D);
        ax += w0 * v0.x; ay += w0 * v0.y; az += w0 * v0.z; aw += w0 * v0.w;
        ax += w1 * v1.x; ay += w1 * v1.y; az += w1 * v1.z; aw += w1 * v1.w;
        ax += w2 * v2.x; ay += w2 * v2.y; az += w2 * v2.z; aw += w2 * v2.w;
        ax += w3 * v3.x; ay += w3 * v3.y; az += w3 * v3.z; aw += w3 * v3.w;
    }
    // 2 edges at a time
    for (; e + 2 <= e1; e += 2) {
        int i0 = e + half;
        int s0 = csr_src[i0]; float w0 = csr_norm[i0];
        float4 v0 = *(const float4*)(Tc + (size_t)s0 * D);
        ax += w0 * v0.x; ay += w0 * v0.y; az += w0 * v0.z; aw += w0 * v0.w;
    }
    // odd leftover: half 0 only
    if (e < e1 && half == 0) {
        int s0 = csr_src[e]; float w0 = csr_norm[e];
        float4 v0 = *(const float4*)(Tc + (size_t)s0 * D);
        ax += w0 * v0.x; ay += w0 * v0.y; az += w0 * v0.z; aw += w0 * v0.w;
    }

    // cross-half reduction
    ax += __shfl_xor(ax, 32, 64);
    ay += __shfl_xor(ay, 32, 64);
    az += __shfl_xor(az, 32, 64);
    aw += __shfl_xor(aw, 32, 64);

    if (half == 0) {
        const float4 b4 = *(const float4*)(bias + c);
        float4 r = make_float4(ax + b4.x, ay + b4.y, az + b4.z, aw + b4.w);
        *(float4*)(O + (size_t)node * D + c) = r;
    }
}

// ---------------- launch ----------------

extern "C" void kernel_launch(void* const* d_in, const int* in_sizes, int n_in,
                              void* d_out, int out_size, void* d_ws, size_t ws_size,
                              hipStream_t stream) {
    const float* x  = (const float*)d_in[0];
    const int*   ei = (const int*)d_in[1];
    const float* W1 = (const float*)d_in[2];
    const float* b1 = (const float*)d_in[3];
    const float* W2 = (const float*)d_in[4];
    const float* b2 = (const float*)d_in[5];
    const int N = in_sizes[0] / D;
    const int E = in_sizes[1] / 2;
    float* out = (float*)d_out;

    char* ws = (char*)d_ws;
    size_t woff = 0;
    auto alloc = [&](size_t bytes) -> void* {
        void* p = ws + woff;
        woff = (woff + bytes + 15) & ~(size_t)15;
        return p;
    };
    float* T        = (float*)alloc((size_t)N * D * sizeof(float));
    int*   cnt      = (int*)  alloc((size_t)N * sizeof(int));
    int*   offsets  = (int*)  alloc((size_t)(N + 1) * sizeof(int));
    int*   cursor   = (int*)  alloc((size_t)N * sizeof(int));
    float* dinv     = (float*)alloc((size_t)N * sizeof(float));
    int*   csr_src  = (int*)  alloc((size_t)E * sizeof(int));
    float* csr_norm = (float*)alloc((size_t)E * sizeof(float));
    int*   partials = (int*)  alloc(1024 * sizeof(int));
    int*   base     = (int*)  alloc(1024 * sizeof(int));
    (void)ws_size; (void)n_in; (void)out_size;

    const int* e_src = ei;
    const int* e_dst = ei + E;
    const int NB = (N + 511) / 512;   // 196 <= 512

    k_zero<<<(N + 255) / 256, 256, 0, stream>>>(cnt, N);
    k_count<<<(E + 255) / 256, 256, 0, stream>>>(e_dst, cnt, E);
    k_dinv<<<(N + 255) / 256, 256, 0, stream>>>(cnt, dinv, N);
    k_scanA<<<NB, 256, 0, stream>>>(cnt, partials, N);
    k_scanB<<<1, 512, 0, stream>>>(partials, base, offsets + N, NB);
    k_scanC<<<NB, 256, 0, stream>>>(cnt, base, offsets, cursor, N);
    k_fill<<<(E + 255) / 256, 256, 0, stream>>>(e_src, e_dst, cursor, dinv,
                                                csr_src, csr_norm, E);

    const float* h = x;
    for (int l = 0; l < 5; l++) {
        const float* W = l ? W2 : W1;
        const float* b = l ? b2 : b1;
        k_matmul<<<(N + 127) / 128, 256, 0, stream>>>(h, W, T, N);
        k_gather<<<(N + 3) / 4, 256, 0, stream>>>(T, csr_src, csr_norm, offsets,
                                                  dinv, b, out, N);
        h = out;
    }
}